// Round 1
// baseline (51.559 us; speedup 1.0000x reference)
//
#include <hip/hip_runtime.h>

#define LEVELS 256
#define HH 256
#define WW 256
#define NPIX 65536          // 256*256
#define NIMG 180

// ---------------- bulk copy: image -> out (float4 vectorized) ----------------
__global__ void copy_kernel(const float4* __restrict__ in, float4* __restrict__ out, int n4) {
    int i = blockIdx.x * blockDim.x + threadIdx.x;
    int stride = gridDim.x * blockDim.x;
    for (; i < n4; i += stride) out[i] = in[i];
}

// ---------------- min/max of band (single block, 1024 threads) ---------------
__global__ void minmax_kernel(const float* __restrict__ image,
                              const int* __restrict__ index,
                              float* __restrict__ mm) {
    const float* band = image + (size_t)index[0] * NPIX;
    const float4* b4 = (const float4*)band;
    int tid = threadIdx.x;
    float lo = 3.402823466e38f, hi = -3.402823466e38f;
    for (int i = tid; i < NPIX / 4; i += blockDim.x) {
        float4 v = b4[i];
        lo = fminf(lo, fminf(fminf(v.x, v.y), fminf(v.z, v.w)));
        hi = fmaxf(hi, fmaxf(fmaxf(v.x, v.y), fmaxf(v.z, v.w)));
    }
    // wave-64 butterfly
    for (int o = 32; o > 0; o >>= 1) {
        lo = fminf(lo, __shfl_down(lo, o));
        hi = fmaxf(hi, __shfl_down(hi, o));
    }
    __shared__ float slo[16], shi[16];
    int wave = tid >> 6, lane = tid & 63;
    if (lane == 0) { slo[wave] = lo; shi[wave] = hi; }
    __syncthreads();
    if (tid == 0) {
        int nw = blockDim.x >> 6;
        for (int w = 1; w < nw; ++w) { lo = fminf(lo, slo[w]); hi = fmaxf(hi, shi[w]); }
        mm[0] = lo;
        mm[1] = hi;
    }
}

// ---------------- quantize band to u8 codes ----------------------------------
__global__ void quant_kernel(const float* __restrict__ image,
                             const int* __restrict__ index,
                             const float* __restrict__ mm,
                             unsigned char* __restrict__ codes) {
    int i = blockIdx.x * blockDim.x + threadIdx.x;
    if (i >= NPIX) return;
    const float* band = image + (size_t)index[0] * NPIX;
    float lo = mm[0], hi = mm[1];
    float denom = fmaxf(hi - lo, 1e-12f);
    float s = (band[i] - lo) / denom;   // IEEE div, matches np
    float v = rintf(s * 255.0f);        // round-half-even, matches np.round
    v = fminf(fmaxf(v, 0.0f), 255.0f);
    codes[i] = (unsigned char)v;
}

// ---------------- GLCM histograms (4 offsets) --------------------------------
__global__ void hist_kernel(const unsigned char* __restrict__ codes,
                            unsigned int* __restrict__ hist) {
    int i = blockIdx.x * blockDim.x + threadIdx.x;
    if (i >= NPIX) return;
    int r = i >> 8, c = i & 255;
    int a = codes[i];
    const int drs[4] = {0, 1, 1, 1};
    const int dcs[4] = {1, 1, 0, -1};
#pragma unroll
    for (int k = 0; k < 4; ++k) {
        int rr = r + drs[k], cc = c + dcs[k];
        if (rr < HH && cc >= 0 && cc < WW) {
            int b = codes[(rr << 8) | cc];
            atomicAdd(&hist[k * NPIX + a * LEVELS + b], 1u);
        }
    }
}

// ---------------- variance over the 4 angles ---------------------------------
__global__ void var_kernel(const unsigned int* __restrict__ hist,
                           float* __restrict__ out_var) {
    int i = blockIdx.x * blockDim.x + threadIdx.x;
    if (i >= NPIX) return;
    float c0 = (float)hist[i];
    float c1 = (float)hist[NPIX + i];
    float c2 = (float)hist[2 * NPIX + i];
    float c3 = (float)hist[3 * NPIX + i];
    float m = (c0 + c1 + c2 + c3) * 0.25f;
    float d0 = c0 - m, d1 = c1 - m, d2 = c2 - m, d3 = c3 - m;
    float var = ((d0 * d0 + d1 * d1) + (d2 * d2 + d3 * d3)) * 0.25f;
    out_var[i] = var;
}

extern "C" void kernel_launch(void* const* d_in, const int* in_sizes, int n_in,
                              void* d_out, int out_size, void* d_ws, size_t ws_size,
                              hipStream_t stream) {
    const float* image = (const float*)d_in[0];
    const int* index = (const int*)d_in[1];
    float* out = (float*)d_out;

    // workspace layout:
    //   [0, 4*NPIX*4)                : 4 histograms (uint32)
    //   [4*NPIX*4, 4*NPIX*4 + NPIX)  : u8 codes
    //   next 8-aligned               : 2 floats (min, max)
    unsigned int* hist = (unsigned int*)d_ws;
    unsigned char* codes = (unsigned char*)d_ws + (size_t)4 * NPIX * sizeof(unsigned int);
    float* mm = (float*)((char*)d_ws + (size_t)4 * NPIX * sizeof(unsigned int) + NPIX);

    // zero the histograms (harness does not re-poison ws between replays)
    hipMemsetAsync(hist, 0, (size_t)4 * NPIX * sizeof(unsigned int), stream);

    // bulk copy of the input image into the first 180 channels of out
    int n4 = NIMG * NPIX / 4;
    copy_kernel<<<2048, 256, 0, stream>>>((const float4*)image, (float4*)out, n4);

    // band min/max
    minmax_kernel<<<1, 1024, 0, stream>>>(image, index, mm);

    // quantize to u8
    quant_kernel<<<NPIX / 256, 256, 0, stream>>>(image, index, mm, codes);

    // GLCM histograms
    hist_kernel<<<NPIX / 256, 256, 0, stream>>>(codes, hist);

    // variance -> last channel of out
    var_kernel<<<NPIX / 256, 256, 0, stream>>>(hist, out + (size_t)NIMG * NPIX);
}

// Round 2
// 50.524 us; speedup vs baseline: 1.0205x; 1.0205x over previous
//
#include <hip/hip_runtime.h>

#define LEVELS 256
#define NPIX 65536          // 256*256
#define NIMG 180
#define COPY_BLOCKS 2048

// ---------------- K1: bulk copy + zero hist + band min/max -------------------
__global__ void k1_copy_zero_minmax(const float* __restrict__ image,
                                    const int* __restrict__ index,
                                    float* __restrict__ out,
                                    unsigned int* __restrict__ hist,
                                    float* __restrict__ mm) {
    if (blockIdx.x < COPY_BLOCKS) {
        int gid = blockIdx.x * blockDim.x + threadIdx.x;
        // zero the 4 histograms (4*NPIX uints = 1 MB) as uint4 stores
        if (gid < NPIX) {
            ((uint4*)hist)[gid] = make_uint4(0u, 0u, 0u, 0u);
        }
        const float4* in4 = (const float4*)image;
        float4* out4 = (float4*)out;
        const int n4 = NIMG * NPIX / 4;
        const int stride = COPY_BLOCKS * 256;
        for (int i = gid; i < n4; i += stride) out4[i] = in4[i];
    } else {
        // single extra block: min/max of the selected band (256 KB)
        const float* band = image + (size_t)index[0] * NPIX;
        const float4* b4 = (const float4*)band;
        int tid = threadIdx.x;
        float lo = 3.402823466e38f, hi = -3.402823466e38f;
        for (int i = tid; i < NPIX / 4; i += 256) {
            float4 v = b4[i];
            lo = fminf(lo, fminf(fminf(v.x, v.y), fminf(v.z, v.w)));
            hi = fmaxf(hi, fmaxf(fmaxf(v.x, v.y), fmaxf(v.z, v.w)));
        }
        for (int o = 32; o > 0; o >>= 1) {
            lo = fminf(lo, __shfl_down(lo, o));
            hi = fmaxf(hi, __shfl_down(hi, o));
        }
        __shared__ float slo[4], shi[4];
        int wave = tid >> 6, lane = tid & 63;
        if (lane == 0) { slo[wave] = lo; shi[wave] = hi; }
        __syncthreads();
        if (tid == 0) {
            for (int w = 1; w < 4; ++w) { lo = fminf(lo, slo[w]); hi = fmaxf(hi, shi[w]); }
            mm[0] = lo;
            mm[1] = hi;
        }
    }
}

// ---------------- K2: fused quantize + GLCM histogram ------------------------
__device__ __forceinline__ int quant_code(const float* band, int j, float lo, float denom) {
    float s = (band[j] - lo) / denom;   // IEEE div, matches np
    float v = rintf(s * 255.0f);        // round-half-even, matches np.round
    v = fminf(fmaxf(v, 0.0f), 255.0f);
    return (int)v;
}

__global__ void k2_hist(const float* __restrict__ image,
                        const int* __restrict__ index,
                        const float* __restrict__ mm,
                        unsigned int* __restrict__ hist) {
    int i = blockIdx.x * blockDim.x + threadIdx.x;
    if (i >= NPIX) return;
    const float* band = image + (size_t)index[0] * NPIX;
    float lo = mm[0];
    float denom = fmaxf(mm[1] - lo, 1e-12f);
    int r = i >> 8, c = i & 255;
    int a = quant_code(band, i, lo, denom);
    // offsets: (0,1), (1,1), (1,0), (1,-1)
    if (c + 1 < 256) {
        int b = quant_code(band, i + 1, lo, denom);
        atomicAdd(&hist[0 * NPIX + a * LEVELS + b], 1u);
    }
    if (r + 1 < 256) {
        if (c + 1 < 256) {
            int b = quant_code(band, i + 257, lo, denom);
            atomicAdd(&hist[1 * NPIX + a * LEVELS + b], 1u);
        }
        {
            int b = quant_code(band, i + 256, lo, denom);
            atomicAdd(&hist[2 * NPIX + a * LEVELS + b], 1u);
        }
        if (c - 1 >= 0) {
            int b = quant_code(band, i + 255, lo, denom);
            atomicAdd(&hist[3 * NPIX + a * LEVELS + b], 1u);
        }
    }
}

// ---------------- K3: variance over the 4 angles -----------------------------
__global__ void k3_var(const unsigned int* __restrict__ hist,
                       float* __restrict__ out_var) {
    int i = blockIdx.x * blockDim.x + threadIdx.x;
    if (i >= NPIX) return;
    float c0 = (float)hist[i];
    float c1 = (float)hist[NPIX + i];
    float c2 = (float)hist[2 * NPIX + i];
    float c3 = (float)hist[3 * NPIX + i];
    float m = (c0 + c1 + c2 + c3) * 0.25f;
    float d0 = c0 - m, d1 = c1 - m, d2 = c2 - m, d3 = c3 - m;
    out_var[i] = ((d0 * d0 + d1 * d1) + (d2 * d2 + d3 * d3)) * 0.25f;
}

extern "C" void kernel_launch(void* const* d_in, const int* in_sizes, int n_in,
                              void* d_out, int out_size, void* d_ws, size_t ws_size,
                              hipStream_t stream) {
    const float* image = (const float*)d_in[0];
    const int* index = (const int*)d_in[1];
    float* out = (float*)d_out;

    // workspace layout:
    //   [0, 4*NPIX*4)    : 4 histograms (uint32), zeroed in K1 each call
    //   next             : 2 floats (min, max)
    unsigned int* hist = (unsigned int*)d_ws;
    float* mm = (float*)((char*)d_ws + (size_t)4 * NPIX * sizeof(unsigned int));

    // K1: copy image -> out, zero hist, compute band min/max (extra block)
    k1_copy_zero_minmax<<<COPY_BLOCKS + 1, 256, 0, stream>>>(image, index, out, hist, mm);

    // K2: fused quantize + GLCM histogram
    k2_hist<<<NPIX / 256, 256, 0, stream>>>(image, index, mm, hist);

    // K3: variance -> last channel of out
    k3_var<<<NPIX / 256, 256, 0, stream>>>(hist, out + (size_t)NIMG * NPIX);
}